// Round 1
// baseline (114.714 us; speedup 1.0000x reference)
//
#include <hip/hip_runtime.h>

#define IMG_W 512
#define NB 32

// ---------------- X: cumsum along width (contiguous axis) ----------------
// One wave (64 lanes) per row. Each lane handles 4 contiguous floats per
// iteration via float4 (64 lanes * 16B = 1024B fully coalesced), two
// iterations cover the 512-wide row with a serial carry between halves.
__device__ __forceinline__ void row_cumsum_wave(const float* __restrict__ in,
                                                float* __restrict__ out,
                                                int gwave) {
    const int lane = threadIdx.x & 63;
    const int b = gwave >> 9;          // gwave / 512
    const int row = gwave & 511;
    const long base = ((long)(b * 2 + 0) * IMG_W + row) * IMG_W;

    float carry = 0.f;
#pragma unroll
    for (int it = 0; it < 2; ++it) {
        const int e = it * 256 + lane * 4;
        const float4 v = *reinterpret_cast<const float4*>(in + base + e);
        // in-lane inclusive prefix of the 4 elements
        const float c0 = v.x;
        const float c1 = c0 + v.y;
        const float c2 = c1 + v.z;
        const float c3 = c2 + v.w;
        // wave-inclusive scan of lane totals (6 shfl_up steps, width 64)
        float t = c3;
#pragma unroll
        for (int d = 1; d < 64; d <<= 1) {
            const float u = __shfl_up(t, d);
            if (lane >= d) t += u;
        }
        const float excl = (t - c3) + carry;   // sum of all elements before this lane
        float4 o;
        o.x = excl + c0;
        o.y = excl + c1;
        o.z = excl + c2;
        o.w = excl + c3;
        *reinterpret_cast<float4*>(out + base + e) = o;
        carry += __shfl(t, 63);                // total of this 256-elem half
    }
}

// ---------------- Y: cumsum along height (stride-512 axis) ----------------
// Reduce-then-scan over S segments of ROWS = 512/S rows.
// Phase A (fused into k1): per-(b, colgroup, seg) block, thread-per-column
// sums its segment's rows -> ws[b][seg][col].
// Phase B (k2): thread-per-column sums preceding segment totals as offset,
// then streams its ROWS rows writing the running cumsum.

template <int S>
__global__ __launch_bounds__(256) void k1_fused(const float* __restrict__ in,
                                                float* __restrict__ out,
                                                float* __restrict__ ws,
                                                int xblocks) {
    if ((int)blockIdx.x < xblocks) {
        // ---- X work: 4 waves per block, one row per wave ----
        const int gwave = blockIdx.x * 4 + (threadIdx.x >> 6);
        row_cumsum_wave(in, out, gwave);
    } else {
        // ---- Y phase A: segment column totals ----
        constexpr int ROWS = IMG_W / S;
        int yb = blockIdx.x - xblocks;         // [0, NB*2*S)
        const int s = yb % S;
        const int g = (yb / S) & 1;            // column group (0..1), 256 cols each
        const int b = yb / (2 * S);
        const int col = g * 256 + threadIdx.x;
        const long ibase = ((long)(b * 2 + 1) * IMG_W + (long)s * ROWS) * IMG_W + col;
        float acc = 0.f;
#pragma unroll
        for (int r = 0; r < ROWS; ++r) acc += in[ibase + (long)r * IMG_W];
        ws[((long)b * S + s) * IMG_W + col] = acc;
    }
}

template <int S>
__global__ __launch_bounds__(256) void k2_scan(const float* __restrict__ in,
                                               float* __restrict__ out,
                                               const float* __restrict__ ws) {
    constexpr int ROWS = IMG_W / S;
    const int yb = blockIdx.x;                 // [0, NB*2*S)
    const int s = yb % S;
    const int g = (yb / S) & 1;
    const int b = yb / (2 * S);
    const int col = g * 256 + threadIdx.x;

    // offset = sum of totals of preceding segments (coalesced ws reads)
    float acc = 0.f;
    for (int t = 0; t < s; ++t) acc += ws[((long)b * S + t) * IMG_W + col];

    const long ibase = ((long)(b * 2 + 1) * IMG_W + (long)s * ROWS) * IMG_W + col;
#pragma unroll 8
    for (int r = 0; r < ROWS; ++r) {
        acc += in[ibase + (long)r * IMG_W];
        out[ibase + (long)r * IMG_W] = acc;
    }
}

template <int S>
static void launch_impl(const float* in, float* out, float* ws, hipStream_t stream) {
    const int xblocks = (NB * IMG_W) / 4;          // 4096 blocks (4 rows/block)
    const int yblocks = NB * 2 * S;                // phase A / B blocks
    k1_fused<S><<<xblocks + yblocks, 256, 0, stream>>>(in, out, ws, xblocks);
    k2_scan<S><<<yblocks, 256, 0, stream>>>(in, out, ws);
}

extern "C" void kernel_launch(void* const* d_in, const int* in_sizes, int n_in,
                              void* d_out, int out_size, void* d_ws, size_t ws_size,
                              hipStream_t stream) {
    const float* in = (const float*)d_in[0];
    float* out = (float*)d_out;
    float* ws = (float*)d_ws;

    // ws need: NB * S * IMG_W floats
    const size_t per_seg = (size_t)NB * IMG_W * sizeof(float);  // 64 KiB per segment
    if (ws_size >= 16 * per_seg)      launch_impl<16>(in, out, ws, stream);
    else if (ws_size >= 8 * per_seg)  launch_impl<8>(in, out, ws, stream);
    else if (ws_size >= 4 * per_seg)  launch_impl<4>(in, out, ws, stream);
    else if (ws_size >= 2 * per_seg)  launch_impl<2>(in, out, ws, stream);
    else                              launch_impl<1>(in, out, ws, stream);
}